// Round 3
// baseline (689.017 us; speedup 1.0000x reference)
//
#include <hip/hip_runtime.h>
#include <hip/hip_bf16.h>

typedef __bf16 bf16;
typedef bf16 bf16x8 __attribute__((ext_vector_type(8)));
typedef float f32x4 __attribute__((ext_vector_type(4)));

#define MFMA16(a, b, c) __builtin_amdgcn_mfma_f32_16x16x32_bf16((a), (b), (c), 0, 0, 0)

__device__ __forceinline__ float fast_rcp(float x) { return __builtin_amdgcn_rcpf(x); }
__device__ __forceinline__ float fast_rsq(float x) { return __builtin_amdgcn_rsqf(x); }
__device__ __forceinline__ float fast_tanh(float x) {
    float e = __expf(2.0f * x);
    return 1.0f - 2.0f * fast_rcp(e + 1.0f);
}
__device__ __forceinline__ float fast_sigmoid(float x) {
    return fast_rcp(1.0f + __expf(-x));
}

// load 8 consecutive fp32 and round to bf16x8 (MFMA operand)
__device__ __forceinline__ bf16x8 cvt8(const float* __restrict__ p) {
    f32x4 a = *(const f32x4*)p;
    f32x4 b = *(const f32x4*)(p + 4);
    bf16x8 r;
    r[0] = (bf16)a[0]; r[1] = (bf16)a[1]; r[2] = (bf16)a[2]; r[3] = (bf16)a[3];
    r[4] = (bf16)b[0]; r[5] = (bf16)b[1]; r[6] = (bf16)b[2]; r[7] = (bf16)b[3];
    return r;
}

// ws layout (bytes):
//   [0,    8192)  Wf  bf16[64][64]  = W_mlp[:,0:64] @ W_init   (fused e-path weight)
//   [8192, 8320)  waf bf16[64]      = w_alpha[0:64] @ W_init
//   [8320, 8576)  bMf f32[64]       = b_mlp + W_mlp[:,0:64] @ b_init
//   [8576, 8580)  bAf f32[1]        = b_alpha + w_alpha[0:64] . b_init
#define WS_WAF  8192
#define WS_BMF  8320
#define WS_BAF  8576

__global__ void fuse_weights_kernel(const float* __restrict__ W_init,
                                    const float* __restrict__ b_init,
                                    const float* __restrict__ W_mlp,
                                    const float* __restrict__ b_mlp,
                                    const float* __restrict__ W_alpha,
                                    const float* __restrict__ b_alpha,
                                    char* __restrict__ ws)
{
    bf16*  Wf  = (bf16*)ws;
    bf16*  waf = (bf16*)(ws + WS_WAF);
    float* bMf = (float*)(ws + WS_BMF);
    float* bAf = (float*)(ws + WS_BAF);
    const int idx = blockIdx.x * 256 + threadIdx.x;
    if (idx < 4096) {
        const int o = idx >> 6, k = idx & 63;
        float acc = 0.f;
        for (int j = 0; j < 64; ++j)
            acc += W_mlp[o * 192 + j] * W_init[j * 64 + k];
        Wf[o * 64 + k] = (bf16)acc;
    } else if (idx < 4160) {
        const int o = idx - 4096;
        float acc = b_mlp[o];
        for (int j = 0; j < 64; ++j)
            acc += W_mlp[o * 192 + j] * b_init[j];
        bMf[o] = acc;
    } else if (idx < 4224) {
        const int k = idx - 4160;
        float acc = 0.f;
        for (int j = 0; j < 64; ++j)
            acc += W_alpha[j] * W_init[j * 64 + k];
        waf[k] = (bf16)acc;
    } else if (idx == 4224) {
        float acc = b_alpha[0];
        for (int j = 0; j < 64; ++j)
            acc += W_alpha[j] * b_init[j];
        bAf[0] = acc;
    }
}

// One wave = 16 edges. GEMM-R: e = ef@Wi^T (residual, stays in C-layout regs).
// GEMM2: K=192 over [ef(fused) | head | tail] with [Wf|Wm23 ; waf|wa23].
// fp32 global I/O; bf16 MFMA internally.
__global__ __launch_bounds__(256, 3)
void edge_update_kernel(const float* __restrict__ node_fts,
                        const float* __restrict__ edge_fts,
                        const int*   __restrict__ edges,
                        const float* __restrict__ W_init,
                        const float* __restrict__ b_init,
                        const float* __restrict__ W_mlp,
                        const float* __restrict__ W_alpha,
                        const char*  __restrict__ ws,
                        float* __restrict__ out,
                        int E)
{
    __shared__ bf16 sW2[64][200];  // [out][k=192] cols 0..63 = Wf, 64..191 = W_mlp
    __shared__ bf16 sWa[224];      // k=192: cols 0..63 = waf, 64..191 = W_alpha

    const int tid  = threadIdx.x;
    const int lane = tid & 63;
    const int wv   = tid >> 6;
    const int n    = lane & 15;   // MFMA col n / A-row m
    const int q    = lane >> 4;   // quad

    const bf16*  Wf  = (const bf16*)ws;
    const bf16*  waf = (const bf16*)(ws + WS_WAF);
    const float* bMf = (const float*)(ws + WS_BMF);
    const float* bAf = (const float*)(ws + WS_BAF);

    // ---- stage fused W2 + wa into LDS as bf16 ----
    for (int c = tid; c < 64 * 24; c += 256) {
        const int r = c / 24;
        const int o = (c - r * 24) * 8;
        if (o < 64) *(bf16x8*)(&sW2[r][o]) = *(const bf16x8*)(Wf + r * 64 + o);
        else        *(bf16x8*)(&sW2[r][o]) = cvt8(W_mlp + r * 192 + o);
    }
    if (tid < 24) {
        const int o = tid * 8;
        if (o < 64) *(bf16x8*)(&sWa[o]) = *(const bf16x8*)(waf + o);
        else        *(bf16x8*)(&sWa[o]) = cvt8(W_alpha + o);
    }
    __syncthreads();

    // ---- W_init B-frags in registers: B[k][col] = W_init[col][k] ----
    bf16x8 B1[2][4];
#pragma unroll
    for (int kk = 0; kk < 2; ++kk)
#pragma unroll
        for (int t = 0; t < 4; ++t)
            B1[kk][t] = cvt8(W_init + (t * 16 + n) * 64 + kk * 32 + q * 8);

    float bI[4], bM[4];
#pragma unroll
    for (int t = 0; t < 4; ++t) {
        bI[t] = b_init[t * 16 + n];
        bM[t] = bMf[t * 16 + n];
    }
    const float bA = bAf[0];

    const int ngroups = E >> 4;
    for (int g = blockIdx.x * 4 + wv; g < ngroups; g += gridDim.x * 4) {
        const int e0 = g << 4;
        const int h  = edges[e0 + n];
        const int tl = edges[E + e0 + n];

        // A-fragments: lane's A-row m = n; k = seg*32 + q*8 + j (contiguous fp32 -> bf16)
        bf16x8 A[6];
        A[0] = cvt8(edge_fts + (e0 + n) * 64 +      q * 8);
        A[1] = cvt8(edge_fts + (e0 + n) * 64 + 32 + q * 8);
        A[2] = cvt8(node_fts + h  * 64 +      q * 8);
        A[3] = cvt8(node_fts + h  * 64 + 32 + q * 8);
        A[4] = cvt8(node_fts + tl * 64 +      q * 8);
        A[5] = cvt8(node_fts + tl * 64 + 32 + q * 8);

        // ---- GEMM-R: e (residual) in C-layout ----
        f32x4 accE[4] = { f32x4{0,0,0,0}, f32x4{0,0,0,0}, f32x4{0,0,0,0}, f32x4{0,0,0,0} };
#pragma unroll
        for (int kk = 0; kk < 2; ++kk)
#pragma unroll
            for (int t = 0; t < 4; ++t) accE[t] = MFMA16(A[kk], B1[kk][t], accE[t]);

        // ---- GEMM2: K=192, 4 N-tiles + broadcast alpha column ----
        f32x4 accP[4] = { f32x4{0,0,0,0}, f32x4{0,0,0,0}, f32x4{0,0,0,0}, f32x4{0,0,0,0} };
        f32x4 accA = f32x4{0,0,0,0};
#pragma unroll
        for (int kk = 0; kk < 6; ++kk) {
            accA = MFMA16(A[kk], *(const bf16x8*)(&sWa[kk * 32 + q * 8]), accA);
#pragma unroll
            for (int t = 0; t < 4; ++t)
                accP[t] = MFMA16(A[kk], *(const bf16x8*)(&sW2[t * 16 + n][kk * 32 + q * 8]), accP[t]);
        }

        // ---- epilogue: lane holds rows q*4+r, cols t*16+n ----
        float eF[4][4], p[4][4], alpha[4];
#pragma unroll
        for (int t = 0; t < 4; ++t)
#pragma unroll
            for (int r = 0; r < 4; ++r) eF[t][r] = accE[t][r] + bI[t];
#pragma unroll
        for (int r = 0; r < 4; ++r) alpha[r] = fast_sigmoid(accA[r] + bA);
#pragma unroll
        for (int t = 0; t < 4; ++t)
#pragma unroll
            for (int r = 0; r < 4; ++r) p[t][r] = fast_tanh(accP[t][r] + bM[t]);

        // LN1 over 64 cols: per-lane partial over 4 tiles, xor-reduce over 16 n-lanes
        float s1[4], s2[4];
#pragma unroll
        for (int r = 0; r < 4; ++r) {
            s1[r] = p[0][r] + p[1][r] + p[2][r] + p[3][r];
            s2[r] = p[0][r]*p[0][r] + p[1][r]*p[1][r] + p[2][r]*p[2][r] + p[3][r]*p[3][r];
        }
#pragma unroll
        for (int d = 1; d < 16; d <<= 1)
#pragma unroll
            for (int r = 0; r < 4; ++r) {
                s1[r] += __shfl_xor(s1[r], d, 64);
                s2[r] += __shfl_xor(s2[r], d, 64);
            }

        float o2[4][4];
#pragma unroll
        for (int r = 0; r < 4; ++r) {
            const float mean = s1[r] * 0.015625f;
            const float var  = fmaxf(s2[r] * 0.015625f - mean * mean, 0.0f);
            const float rs   = fast_rsq(var + 1e-5f);
#pragma unroll
            for (int t = 0; t < 4; ++t)
                o2[t][r] = eF[t][r] + (p[t][r] - mean) * rs * alpha[r];
        }

        // LN2
#pragma unroll
        for (int r = 0; r < 4; ++r) {
            s1[r] = o2[0][r] + o2[1][r] + o2[2][r] + o2[3][r];
            s2[r] = o2[0][r]*o2[0][r] + o2[1][r]*o2[1][r] + o2[2][r]*o2[2][r] + o2[3][r]*o2[3][r];
        }
#pragma unroll
        for (int d = 1; d < 16; d <<= 1)
#pragma unroll
            for (int r = 0; r < 4; ++r) {
                s1[r] += __shfl_xor(s1[r], d, 64);
                s2[r] += __shfl_xor(s2[r], d, 64);
            }
#pragma unroll
        for (int r = 0; r < 4; ++r) {
            const float mean = s1[r] * 0.015625f;
            const float var  = fmaxf(s2[r] * 0.015625f - mean * mean, 0.0f);
            const float rs   = fast_rsq(var + 1e-5f);
#pragma unroll
            for (int t = 0; t < 4; ++t)
                out[(e0 + q * 4 + r) * 64 + t * 16 + n] = (o2[t][r] - mean) * rs;
        }
    }
}

extern "C" void kernel_launch(void* const* d_in, const int* in_sizes, int n_in,
                              void* d_out, int out_size, void* d_ws, size_t ws_size,
                              hipStream_t stream) {
    const float* node_fts = (const float*)d_in[0];
    const float* edge_fts = (const float*)d_in[1];
    const int*   edges    = (const int*)d_in[2];
    const float* W_init   = (const float*)d_in[3];
    const float* b_init   = (const float*)d_in[4];
    const float* W_mlp    = (const float*)d_in[5];
    const float* b_mlp    = (const float*)d_in[6];
    const float* W_alpha  = (const float*)d_in[7];
    const float* b_alpha  = (const float*)d_in[8];
    float* out = (float*)d_out;
    char*  ws  = (char*)d_ws;

    const int E = in_sizes[2] / 2;  // edges is [2, E]

    hipLaunchKernelGGL(fuse_weights_kernel, dim3(17), dim3(256), 0, stream,
                       W_init, b_init, W_mlp, b_mlp, W_alpha, b_alpha, ws);
    hipLaunchKernelGGL(edge_update_kernel, dim3(2048), dim3(256), 0, stream,
                       node_fts, edge_fts, edges, W_init, b_init,
                       W_mlp, W_alpha, ws, out, E);
}